// Round 2
// 396.432 us; speedup vs baseline: 1.1298x; 1.1298x over previous
//
#include <hip/hip_runtime.h>
#include <hip/hip_bf16.h>
#include <cstdint>

typedef __bf16 bf16;
typedef __bf16 bf16x8 __attribute__((ext_vector_type(8)));
typedef __bf16 bf16x4 __attribute__((ext_vector_type(4)));
typedef float f32x4 __attribute__((ext_vector_type(4)));
typedef int i32x4 __attribute__((ext_vector_type(4)));

#define HIDC 96
#define CINC 192
#define EPSC 1e-5f

// wpack layout: 56 stages (28 offs x 2 halves) x 20480 B. Real payload per
// stage = 18 cix x 1024 B = 18432 B (+2048 B pad -> uniform 16B chunks per
// thread). cix = kc_local*6+ct, element =
//   W[off][k = (half*3+kc_local)*32 + (lane>>4)*8 + j][col = ct*16 + (lane&15)]
#define STG_B 20480
#define STG_ELEM 10240

// async global->LDS, 16B per lane, wave-uniform LDS base + lane*16
#define GLD_LDS16(g, l)                                                        \
  __builtin_amdgcn_global_load_lds(                                            \
      (const __attribute__((address_space(1))) void*)(g),                      \
      (__attribute__((address_space(3))) void*)(l), 16, 0, 0)

// ---------------------------------------------------------------------------
// K0: repack W_conv [27][192][96] fp32 + W_lin [192][96] fp32 -> bf16 wpack.
// ---------------------------------------------------------------------------
__global__ void k_repack(const float* __restrict__ Wc, const float* __restrict__ Wl,
                         bf16* __restrict__ dst, int total) {
  int t = blockIdx.x * 256 + threadIdx.x;
  if (t >= total) return;              // total = 28*18432 real elements
  int off = t / 18432;
  int rem = t - off * 18432;
  int cix = rem >> 9;
  int lane = (rem >> 3) & 63;
  int j = rem & 7;
  int k = (cix / 6) * 32 + ((lane >> 4) << 3) + j;
  int col = (cix % 6) * 16 + (lane & 15);
  const float* src = (off < 27) ? (Wc + ((size_t)off * CINC + k) * HIDC + col)
                                : (Wl + (size_t)k * HIDC + col);
  int half = (cix >= 18) ? 1 : 0;
  size_t de = (size_t)(off * 2 + half) * STG_ELEM + (size_t)(rem - half * 9216);
  dst[de] = (bf16)(*src);
}

// ---------------------------------------------------------------------------
// Voxelize path: counting-sort + gather-mean (replaces 23M fp32 atomics).
// ---------------------------------------------------------------------------
__global__ void k_count(const int* __restrict__ seg, int* __restrict__ cnt, int Npts) {
  int t = blockIdx.x * 256 + threadIdx.x;
  if (t < Npts) atomicAdd(cnt + seg[t], 1);
}

__global__ void k_bsum(const int* __restrict__ cnt, int* __restrict__ bsum, int M) {
  __shared__ int sm[256];
  int i = blockIdx.x * 256 + threadIdx.x;
  sm[threadIdx.x] = (i < M) ? cnt[i] : 0;
  __syncthreads();
  for (int st = 128; st > 0; st >>= 1) {
    if (threadIdx.x < st) sm[threadIdx.x] += sm[threadIdx.x + st];
    __syncthreads();
  }
  if (threadIdx.x == 0) bsum[blockIdx.x] = sm[0];
}

// exclusive scan of nb (<=1024) block sums, in place
__global__ void k_bscan(int* __restrict__ bsum, int nb) {
  __shared__ int sm[1024];
  int i = threadIdx.x;
  int v = (i < nb) ? bsum[i] : 0;
  sm[i] = v;
  __syncthreads();
  for (int st = 1; st < 1024; st <<= 1) {
    int t = (i >= st) ? sm[i - st] : 0;
    __syncthreads();
    sm[i] += t;
    __syncthreads();
  }
  if (i < nb) bsum[i] = sm[i] - v;
}

__global__ void k_ptr(const int* __restrict__ cnt, const int* __restrict__ bsum,
                      int* __restrict__ ptr, int* __restrict__ cursor, int M) {
  __shared__ int sm[256];
  int i = blockIdx.x * 256 + threadIdx.x;
  int v = (i < M) ? cnt[i] : 0;
  sm[threadIdx.x] = v;
  __syncthreads();
  for (int st = 1; st < 256; st <<= 1) {
    int t = (threadIdx.x >= st) ? sm[threadIdx.x - st] : 0;
    __syncthreads();
    sm[threadIdx.x] += t;
    __syncthreads();
  }
  if (i < M) {
    int e = bsum[blockIdx.x] + sm[threadIdx.x] - v;
    ptr[i] = e;
    cursor[i] = e;
  }
}

__global__ void k_scatter(const int* __restrict__ seg, int* __restrict__ cursor,
                          int* __restrict__ plist, int Npts) {
  int t = blockIdx.x * 256 + threadIdx.x;
  if (t < Npts) {
    int pos = atomicAdd(cursor + seg[t], 1);
    plist[pos] = t;
  }
}

// per (voxel, 4-channel group): mean of member point features -> bf16 vpad.
__global__ void k_gmean(const float* __restrict__ hid, const float* __restrict__ qry,
                        const int* __restrict__ ptr, const int* __restrict__ cnt,
                        const int* __restrict__ plist, bf16* __restrict__ vpad, int M) {
  int t = blockIdx.x * 256 + threadIdx.x;
  if (t >= (M + 1) * 48) return;
  int v = t / 48;
  int q = t - v * 48;
  f32x4 a = {0.f, 0.f, 0.f, 0.f};
  if (v < M) {
    int st = ptr[v], n = cnt[v];
    const float* base = (q < 24) ? (hid + q * 4) : (qry + (q - 24) * 4);
    for (int j = 0; j < n; j++) {
      int p = plist[st + j];
      a += *(const f32x4*)(base + (size_t)p * HIDC);
    }
    a *= (1.0f / (float)(n > 0 ? n : 1));
  }
  bf16x4 o;
#pragma unroll
  for (int j = 0; j < 4; j++) o[j] = (bf16)a[j];
  *(bf16x4*)(vpad + (size_t)v * CINC + q * 4) = o;
}

// ---------------------------------------------------------------------------
// K3: sparse conv. 128 thr = 2 waves; each wave owns 4 row-tiles (rt=4) so
// each B ds_read feeds 4 MFMAs (half the LDS read traffic of rt=2). B
// double-buffered in LDS via global_load_lds (16B, linear dest = wave-uniform
// base + lane*16, no register round-trip). A fragments reloaded in place at
// kc2 granularity one stage ahead; BN column stats fused into the epilogue
// (block owns its 128 rows end-to-end, plain stores).
// ---------------------------------------------------------------------------
__launch_bounds__(128, 2)
__global__ void k_conv(const bf16* __restrict__ vpad, const int* __restrict__ nbr,
                       const bf16* __restrict__ wpack, float* __restrict__ accbuf,
                       float* __restrict__ bnsum, int M, int nblk, int nper) {
  const int bx = (int)(blockIdx.x & 7) * nper + (int)(blockIdx.x >> 3);
  if (bx >= nblk) return;
  __shared__ bf16 Bb[2][STG_B / 2];  // 2 x 20KB
  const int tid = threadIdx.x;
  const int wave = tid >> 6;
  const int lane = tid & 63;
  const int m = lane & 15;
  const int quad = lane >> 4;
  const int rb = bx * 128 + wave * 64;

  f32x4 acc[4][6];
#pragma unroll
  for (int rt = 0; rt < 4; rt++)
#pragma unroll
    for (int ct = 0; ct < 6; ct++) {
      f32x4 z = {0.f, 0.f, 0.f, 0.f};
      acc[rt][ct] = z;
    }

  const char* wb = (const char*)wpack;
  // prologue: stage-0 B into buf0 (async), gidx + A frags for stage 0
  {
    char* dstb = (char*)&Bb[0][0];
#pragma unroll
    for (int i = 0; i < 10; i++) {
      const int base = (wave * 64 + i * 128) * 16;
      GLD_LDS16(wb + base + lane * 16, dstb + base);
    }
  }
  int gidx[4], gidx2[4];
#pragma unroll
  for (int rt = 0; rt < 4; rt++) {
    int r = rb + rt * 16 + m;
    gidx[rt] = (r < M) ? nbr[(size_t)r * 27] : M;
  }
  bf16x8 af[4][3];
#pragma unroll
  for (int kc2 = 0; kc2 < 3; kc2++)
#pragma unroll
    for (int rt = 0; rt < 4; rt++)
      af[rt][kc2] = *(const bf16x8*)(vpad + (size_t)gidx[rt] * CINC + kc2 * 32 + quad * 8);
  __syncthreads();  // drains vmcnt: stage-0 B in LDS, af ready

  for (int s = 0; s < 54; s++) {
    const int buf = s & 1;
    // issue next-stage B staging (lands in buf^1; drained at stage-end sync)
    if (s < 53) {
      const char* src = wb + (size_t)(s + 1) * STG_B;
      char* dstb = (char*)&Bb[buf ^ 1][0];
#pragma unroll
      for (int i = 0; i < 10; i++) {
        const int base = (wave * 64 + i * 128) * 16;
        GLD_LDS16(src + base + lane * 16, dstb + base);
      }
    }
    const int half = s & 1;
    const int off = s >> 1;
    if (half == 0) {
      const int offn = off + 1;
#pragma unroll
      for (int rt = 0; rt < 4; rt++) {
        int r = rb + rt * 16 + m;
        gidx2[rt] = (r < M && offn < 27) ? nbr[(size_t)r * 27 + offn] : M;
      }
    }
    const char* bbr = (const char*)&Bb[buf][0];
#pragma unroll
    for (int kc2 = 0; kc2 < 3; kc2++) {
#pragma unroll
      for (int ct = 0; ct < 6; ct++) {
        bf16x8 bfm = *(const bf16x8*)(bbr + (size_t)(kc2 * 6 + ct) * 1024 + (size_t)lane * 16);
#pragma unroll
        for (int rt = 0; rt < 4; rt++)
          acc[rt][ct] = __builtin_amdgcn_mfma_f32_16x16x32_bf16(af[rt][kc2], bfm, acc[rt][ct], 0, 0, 0);
      }
      // af[.][kc2] is dead now in this stage: reload in place for stage s+1
      if (s < 53) {
        if (half == 0) {
#pragma unroll
          for (int rt = 0; rt < 4; rt++)
            af[rt][kc2] = *(const bf16x8*)(vpad + (size_t)gidx[rt] * CINC +
                                           (kc2 + 3) * 32 + quad * 8);
        } else {
#pragma unroll
          for (int rt = 0; rt < 4; rt++)
            af[rt][kc2] = *(const bf16x8*)(vpad + (size_t)gidx2[rt] * CINC +
                                           kc2 * 32 + quad * 8);
        }
      }
    }
    if (half == 1) {
#pragma unroll
      for (int rt = 0; rt < 4; rt++) gidx[rt] = gidx2[rt];
    }
    __syncthreads();  // drains this wave's B staging + af prefetch, phase gate
  }

  // epilogue: plain stores (C layout: row = quad*4+rr, col = ct*16+m) with
  // fused BN column sums/sumsq (replaces k_bnstat's full accbuf re-read)
  float ps[6], pq[6];
#pragma unroll
  for (int ct = 0; ct < 6; ct++) { ps[ct] = 0.f; pq[ct] = 0.f; }
#pragma unroll
  for (int rt = 0; rt < 4; rt++) {
#pragma unroll
    for (int rr = 0; rr < 4; rr++) {
      const int r2 = rb + rt * 16 + quad * 4 + rr;
      if (r2 < M) {
        float* dst = accbuf + (size_t)r2 * HIDC + m;
#pragma unroll
        for (int ct = 0; ct < 6; ct++) {
          float v = acc[rt][ct][rr];
          dst[ct * 16] = v;
          ps[ct] += v;
          pq[ct] += v * v;
        }
      }
    }
  }
#pragma unroll
  for (int ct = 0; ct < 6; ct++) {
    float s1 = ps[ct], s2 = pq[ct];
    s1 += __shfl_xor(s1, 16);
    s2 += __shfl_xor(s2, 16);
    s1 += __shfl_xor(s1, 32);
    s2 += __shfl_xor(s2, 32);
    if (quad == 0) {
      atomicAdd(bnsum + ct * 16 + m, s1);
      atomicAdd(bnsum + 96 + ct * 16 + m, s2);
    }
  }
}

// ---------------------------------------------------------------------------
// K5: y = relu(acc*scale + shift) -> bf16 ypad, zero pad row M. BN finalize
// (scale/shift from raw sums) computed per block into LDS (k_bnfin folded in).
// ---------------------------------------------------------------------------
__global__ void k_bnapply(const float* __restrict__ accbuf, const float* __restrict__ bnsum,
                          const float* __restrict__ gamma, const float* __restrict__ beta,
                          bf16* __restrict__ ypad, int M) {
  __shared__ float ssc[96], ssh[96];
  if (threadIdx.x < 96) {
    int c = threadIdx.x;
    float inv = 1.0f / (float)M;
    float mu = bnsum[c] * inv;
    float var = fmaxf(bnsum[96 + c] * inv - mu * mu, 0.f);
    float sc = gamma[c] * rsqrtf(var + EPSC);
    ssc[c] = sc;
    ssh[c] = beta[c] - mu * sc;
  }
  __syncthreads();
  int t = blockIdx.x * 256 + threadIdx.x;
  if (t >= (M + 1) * 24) return;
  int v = t / 24;
  int g = t - v * 24;
  f32x4 y = {0.f, 0.f, 0.f, 0.f};
  if (v < M) {
    f32x4 a = *(const f32x4*)(accbuf + (size_t)v * HIDC + g * 4);
#pragma unroll
    for (int j = 0; j < 4; j++) y[j] = fmaxf(a[j] * ssc[g * 4 + j] + ssh[g * 4 + j], 0.f);
  }
  bf16x4 o;
#pragma unroll
  for (int j = 0; j < 4; j++) o[j] = (bf16)y[j];
  *(bf16x4*)(ypad + (size_t)v * HIDC + g * 4) = o;
}

// ---------------------------------------------------------------------------
// K6: lin = hx @ W_lin + b_lin (fp32 in, bf16 MFMA, bf16 out). LDS-free,
// 256 thr = 4 waves x 32 rows; B fragments direct from L2-resident wlpack
// (stage-padded layout: half = kc>=3).
// ---------------------------------------------------------------------------
__launch_bounds__(256, 4)
__global__ void k_linear(const float* __restrict__ hid, const float* __restrict__ qry,
                         const bf16* __restrict__ wlpack, const float* __restrict__ blin,
                         bf16* __restrict__ lin, int Npts) {
  const int tid = threadIdx.x;
  const int wave = tid >> 6;
  const int lane = tid & 63;
  const int m = lane & 15;
  const int quad = lane >> 4;
  const int rb = blockIdx.x * 128 + wave * 32;

  f32x4 acc[2][6];
#pragma unroll
  for (int rt = 0; rt < 2; rt++)
#pragma unroll
    for (int ct = 0; ct < 6; ct++) {
      f32x4 z = {0.f, 0.f, 0.f, 0.f};
      acc[rt][ct] = z;
    }

  int prow[2];
#pragma unroll
  for (int rt = 0; rt < 2; rt++) {
    int r = rb + rt * 16 + m;
    prow[rt] = (r < Npts) ? r : (Npts - 1);
  }
  const char* wp = (const char*)wlpack;
#pragma unroll
  for (int kc = 0; kc < 6; kc++) {
    const float* srcA = (kc < 3) ? (hid + kc * 32) : (qry + (kc - 3) * 32);
    bf16x8 af[2];
#pragma unroll
    for (int rt = 0; rt < 2; rt++) {
      const float* pA = srcA + (size_t)prow[rt] * HIDC + quad * 8;
      f32x4 lo = *(const f32x4*)pA;
      f32x4 hi = *(const f32x4*)(pA + 4);
#pragma unroll
      for (int j = 0; j < 4; j++) {
        af[rt][j] = (bf16)lo[j];
        af[rt][4 + j] = (bf16)hi[j];
      }
    }
    const int half = (kc >= 3) ? 1 : 0;
    const int kcl = kc - half * 3;
#pragma unroll
    for (int ct = 0; ct < 6; ct++) {
      bf16x8 bfm = *(const bf16x8*)(wp + (size_t)half * STG_B +
                                    (size_t)((kcl * 6 + ct) * 64 + lane) * 16);
#pragma unroll
      for (int rt = 0; rt < 2; rt++)
        acc[rt][ct] = __builtin_amdgcn_mfma_f32_16x16x32_bf16(af[rt], bfm, acc[rt][ct], 0, 0, 0);
    }
  }
  float bl[6];
#pragma unroll
  for (int ct = 0; ct < 6; ct++) bl[ct] = blin[ct * 16 + m];
#pragma unroll
  for (int rt = 0; rt < 2; rt++)
#pragma unroll
    for (int rr = 0; rr < 4; rr++) {
      const int r2 = rb + rt * 16 + quad * 4 + rr;
      if (r2 < Npts) {
        bf16* dst = lin + (size_t)r2 * HIDC + m;
#pragma unroll
        for (int ct = 0; ct < 6; ct++)
          dst[ct * 16] = (bf16)(acc[rt][ct][rr] + bl[ct]);
      }
    }
}

// ---------------------------------------------------------------------------
// K7: out = lin + sum_k w[p,k] * ypad[cidx[p,k]]  (8-channel groups)
// ---------------------------------------------------------------------------
__global__ void k_out(const bf16* __restrict__ lin, const bf16* __restrict__ ypad,
                      const float* __restrict__ cw, const int* __restrict__ cidx,
                      float* __restrict__ out, int Npts) {
  int t = blockIdx.x * 256 + threadIdx.x;
  if (t >= Npts * 12) return;
  int p = t / 12;
  int g = t - p * 12;
  float a[8];
  bf16x8 lv = *(const bf16x8*)(lin + (size_t)p * HIDC + g * 8);
#pragma unroll
  for (int j = 0; j < 8; j++) a[j] = (float)lv[j];
  f32x4 w0 = *(const f32x4*)(cw + (size_t)p * 8);
  f32x4 w1 = *(const f32x4*)(cw + (size_t)p * 8 + 4);
  const i32x4* cp = (const i32x4*)(cidx + (size_t)p * 8);
  i32x4 c0 = cp[0], c1 = cp[1];
#pragma unroll
  for (int k = 0; k < 8; k++) {
    int idx = (k < 4) ? c0[k] : c1[k - 4];
    float wk = (k < 4) ? w0[k] : w1[k - 4];
    bf16x8 yv = *(const bf16x8*)(ypad + (size_t)idx * HIDC + g * 8);
#pragma unroll
    for (int j = 0; j < 8; j++) a[j] += wk * (float)yv[j];
  }
  float* op = out + (size_t)p * HIDC + g * 8;
  f32x4 s0, s1;
#pragma unroll
  for (int j = 0; j < 4; j++) { s0[j] = a[j]; s1[j] = a[4 + j]; }
  *(f32x4*)op = s0;
  *(f32x4*)(op + 4) = s1;
}

// ---------------------------------------------------------------------------
extern "C" void kernel_launch(void* const* d_in, const int* in_sizes, int n_in,
                              void* d_out, int out_size, void* d_ws, size_t ws_size,
                              hipStream_t stream) {
  const float* hid = (const float*)d_in[0];
  const float* qry = (const float*)d_in[1];
  const float* Wc = (const float*)d_in[2];
  const float* gamma = (const float*)d_in[3];
  const float* beta = (const float*)d_in[4];
  const float* Wl = (const float*)d_in[5];
  const float* blin = (const float*)d_in[6];
  const float* cw = (const float*)d_in[7];
  const int* seg = (const int*)d_in[8];
  const int* nbr = (const int*)d_in[9];
  const int* cidx = (const int*)d_in[10];
  float* out = (float*)d_out;
  const int Npts = in_sizes[0] / HIDC;
  const int M = in_sizes[9] / 27;

  // ---- workspace layout ----
  // [cnt | bnsum]  <- single memset
  // region A: accbuf fp32 [M,96] (K3..K5) -> lin bf16 [N,96] (K6-K7) overlay
  // region B: vpad bf16 [M+1,192] (gmean..conv) -> ypad bf16 [M+1,96] overlay
  char* ws = (char*)d_ws;
  size_t cur = 0;
  auto alloc = [&](size_t b) { size_t o = cur; cur = (cur + b + 255) & ~(size_t)255; return o; };
  size_t o_cnt = alloc((size_t)M * 4);
  size_t o_bn = alloc(192 * 4);
  size_t zend = cur;  // memset range [0, zend): cnt + bnsum
  size_t o_ptr = alloc((size_t)M * 4);
  size_t o_cur = alloc((size_t)M * 4);
  size_t o_pl = alloc((size_t)Npts * 4);
  size_t o_bs = alloc(1024 * 4);
  size_t RA = (size_t)M * HIDC * 4;
  size_t needA = (size_t)Npts * HIDC * 2;
  if (needA > RA) RA = needA;
  size_t o_A = alloc(RA);
  size_t o_B = alloc((size_t)(M + 1) * CINC * 2);
  size_t o_wpack = alloc((size_t)56 * STG_B);
  (void)ws_size; (void)n_in; (void)out_size;

  int* cnt = (int*)(ws + o_cnt);
  float* bnsum = (float*)(ws + o_bn);
  int* ptr = (int*)(ws + o_ptr);
  int* cursor = (int*)(ws + o_cur);
  int* plist = (int*)(ws + o_pl);
  int* bsum = (int*)(ws + o_bs);
  float* accbuf = (float*)(ws + o_A);
  bf16* lin = (bf16*)(ws + o_A);
  bf16* vpad = (bf16*)(ws + o_B);
  bf16* ypad = (bf16*)(ws + o_B);
  bf16* wpack = (bf16*)(ws + o_wpack);
  bf16* wlpack = (bf16*)(ws + o_wpack + (size_t)54 * STG_B);

  // zero cnt + bnsum (adjacent at front; ws poisoned 0xAA each call)
  hipMemsetAsync(ws, 0, zend, stream);

  int totalRepack = 28 * 18432;
  k_repack<<<(totalRepack + 255) / 256, 256, 0, stream>>>(Wc, Wl, wpack, totalRepack);

  // voxelize: count -> scan -> scatter -> gather-mean
  int nb = (M + 255) / 256;
  k_count<<<(Npts + 255) / 256, 256, 0, stream>>>(seg, cnt, Npts);
  k_bsum<<<nb, 256, 0, stream>>>(cnt, bsum, M);
  k_bscan<<<1, 1024, 0, stream>>>(bsum, nb);
  k_ptr<<<nb, 256, 0, stream>>>(cnt, bsum, ptr, cursor, M);
  k_scatter<<<(Npts + 255) / 256, 256, 0, stream>>>(seg, cursor, plist, Npts);
  k_gmean<<<(((M + 1) * 48) + 255) / 256, 256, 0, stream>>>(hid, qry, ptr, cnt, plist, vpad, M);

  int nblk = (M + 127) / 128;
  int nper = (nblk + 7) / 8;
  k_conv<<<nper * 8, 128, 0, stream>>>(vpad, nbr, wpack, accbuf, bnsum, M, nblk, nper);
  k_bnapply<<<((M + 1) * 24 + 255) / 256, 256, 0, stream>>>(accbuf, bnsum, gamma, beta, ypad, M);
  k_linear<<<(Npts + 127) / 128, 256, 0, stream>>>(hid, qry, wlpack, blin, lin, Npts);
  k_out<<<(Npts * 12 + 255) / 256, 256, 0, stream>>>(lin, ypad, cw, cidx, out, Npts);
}